// Round 2
// baseline (65.116 us; speedup 1.0000x reference)
//
#include <hip/hip_runtime.h>
#include <math.h>

// YOLOv1 decode + greedy NMS, S=7 grid, 2 boxes, 20 classes.
// Tiny problem (1470 floats in, 343 out): single block, single wave.
// R2: float4 cooperative staging of input into LDS; NMS loop uses one
// __shfl (keep, the only serial dependency) + wave-uniform LDS broadcast
// reads of the candidate box (rows padded to 8 floats for b128 reads).

#define NUM_CLASSES 20
#define S 7
#define NCELL 49            // S*S boxes
#define NIN 1470            // 1*7*7*30 floats
#define CONF_THR 0.25f
#define IOU_THR 0.45f
#define EPS_IOU 1e-6f
#define CELL_STRIDE 64.0f   // 448 / 7

__device__ __forceinline__ float sigmoidf(float v) {
    return 1.0f / (1.0f + expf(-v));
}

__global__ __launch_bounds__(64) void yolo_decode_nms(const float* __restrict__ x,
                                                      float* __restrict__ out) {
    const int j = threadIdx.x;  // 0..63, one wave

    __shared__ float s_in[1472];            // staged input (pad to x4)
    __shared__ float s_sorted[NCELL][8];    // sorted boxes, row padded to 32B:
                                            // [cls, conf, minx, miny, maxx, maxy, area, pad]
    __shared__ float s_conf[NCELL];         // pre-sort conf for ranking

    // ---- cooperative vectorized staging: 367 float4 + 2-float tail ----
    #pragma unroll
    for (int t = 0; t < 6; ++t) {
        int i4 = t * 64 + j;
        if (i4 < NIN / 4) {                  // 367 full float4s = 1468 floats
            ((float4*)s_in)[i4] = ((const float4*)x)[i4];
        }
    }
    if (j < 2) s_in[1468 + j] = x[1468 + j];
    __syncthreads();

    // ---- decode (lanes 0..48) + rank + scatter directly into sorted array ----
    float cls = 0.f, conf = 0.f, cx = 0.f, cy = 0.f, w = 0.f, h = 0.f;
    if (j < NCELL) {
        const float* c = s_in + j * (NUM_CLASSES + 10);

        // class argmax on raw logits (sigmoid monotonic; first-index ties)
        int ci = 0;
        float cmax = c[0];
        #pragma unroll
        for (int k = 1; k < NUM_CLASSES; ++k) {
            float v = c[k];
            if (v > cmax) { cmax = v; ci = k; }
        }

        // best of 2 boxes by conf logit; tie -> box 0 (jnp.argmax semantics)
        float c0 = c[NUM_CLASSES + 0];
        float c1 = c[NUM_CLASSES + 5];
        int best = (c1 > c0) ? 1 : 0;
        int boff = NUM_CLASSES + 1 + 5 * best;

        conf = sigmoidf(best ? c1 : c0);
        float bx = sigmoidf(c[boff + 0]);
        float by = sigmoidf(c[boff + 1]);
        float bw = sigmoidf(c[boff + 2]);
        float bh = sigmoidf(c[boff + 3]);

        int row = j / S, col = j % S;
        cls = (float)ci;
        cx = (bx + (float)col) * CELL_STRIDE;
        cy = (by + (float)row) * CELL_STRIDE;
        w  = bw * (float)S * CELL_STRIDE;   // bw * W * (448/W) = bw*448
        h  = bh * (float)S * CELL_STRIDE;

        s_conf[j] = conf;
    }
    __syncthreads();

    // stable descending rank (matches jnp.argsort(-conf) stability)
    if (j < NCELL) {
        int rank = 0;
        for (int k = 0; k < NCELL; ++k) {
            float ck = s_conf[k];
            rank += (ck > conf) || (ck == conf && k < j);
        }
        float minx = cx - 0.5f * w, maxx = cx + 0.5f * w;
        float miny = cy - 0.5f * h, maxy = cy + 0.5f * h;
        s_sorted[rank][0] = cls;
        s_sorted[rank][1] = conf;
        s_sorted[rank][2] = minx;
        s_sorted[rank][3] = miny;
        s_sorted[rank][4] = maxx;
        s_sorted[rank][5] = maxy;
        s_sorted[rank][6] = fabsf(w * h);
    }
    __syncthreads();

    // ---- greedy NMS: lane j owns sorted box j ----
    float mcls = 0.f, mconf = 0.f, minx = 0.f, miny = 0.f,
          maxx = 0.f, maxy = 0.f, area = 0.f;
    if (j < NCELL) {
        mcls  = s_sorted[j][0];
        mconf = s_sorted[j][1];
        minx  = s_sorted[j][2];
        miny  = s_sorted[j][3];
        maxx  = s_sorted[j][4];
        maxy  = s_sorted[j][5];
        area  = s_sorted[j][6];
    }
    int keep = (j < NCELL) && (mconf > CONF_THR);

    // Lane i's keep is only modified by iterations < i, so __shfl(keep,i)
    // at iteration i equals the sequential keep[i]. Box-i data comes from
    // wave-uniform LDS reads (broadcast, conflict-free, no serial chain).
    for (int i = 0; i < NCELL; ++i) {
        int keep_i = __shfl(keep, i);
        float icls  = s_sorted[i][0];
        float iminx = s_sorted[i][2];
        float iminy = s_sorted[i][3];
        float imaxx = s_sorted[i][4];
        float imaxy = s_sorted[i][5];
        float iarea = s_sorted[i][6];

        if (j > i && keep && keep_i && mcls == icls) {
            float ix0 = fmaxf(minx, iminx);
            float iy0 = fmaxf(miny, iminy);
            float ix1 = fminf(maxx, imaxx);
            float iy1 = fminf(maxy, imaxy);
            float iw = fmaxf(ix1 - ix0, 0.0f);
            float ih = fmaxf(iy1 - iy0, 0.0f);
            float inter = iw * ih;
            float iou = inter / (iarea + area - inter + EPS_IOU);
            if (iou >= IOU_THR) keep = 0;
        }
    }

    // ---- write: boxes (49*6 cxcywh, zeroed where suppressed) then keep ----
    if (j < NCELL) {
        float kf = keep ? 1.0f : 0.0f;
        float ocx = 0.5f * (minx + maxx);
        float ocy = 0.5f * (miny + maxy);
        float ow  = maxx - minx;
        float oh  = maxy - miny;
        out[j * 6 + 0] = mcls  * kf;
        out[j * 6 + 1] = mconf * kf;
        out[j * 6 + 2] = ocx * kf;
        out[j * 6 + 3] = ocy * kf;
        out[j * 6 + 4] = ow  * kf;
        out[j * 6 + 5] = oh  * kf;
        out[NCELL * 6 + j] = kf;
    }
}

extern "C" void kernel_launch(void* const* d_in, const int* in_sizes, int n_in,
                              void* d_out, int out_size, void* d_ws, size_t ws_size,
                              hipStream_t stream) {
    const float* x = (const float*)d_in[0];
    float* out = (float*)d_out;
    yolo_decode_nms<<<1, 64, 0, stream>>>(x, out);
}